// Round 4
// baseline (152.441 us; speedup 1.0000x reference)
//
#include <hip/hip_runtime.h>
#include <hip/hip_bf16.h>
#include <math.h>

#define B_N 8192
#define D_K 256
#define TILE 128
#define NT 512
#define NBLK 64             // B_N / TILE
#define NPAIR 2080          // NBLK*(NBLK+1)/2 upper-triangular tile pairs
#define NCLS 100
#define LDA 72              // 64 cols + 8 shorts pad: row stride 144B (16B-aligned)
#define KEXP 28.8539008177792681f   // 20*log2(e): e^(sim-20) = 2^((dot-1)*KEXP)

typedef __attribute__((ext_vector_type(8))) short short8;
typedef __attribute__((ext_vector_type(4))) float f32x4;

__device__ __forceinline__ unsigned short f2bf(float x) {
    unsigned int u = __float_as_uint(x);
    unsigned int r = (u + 0x7FFFu + ((u >> 16) & 1u)) >> 16;
    return (unsigned short)r;
}

// -------- Kernel 1: normalize rows -> bf16 matrix + inv_norm --------
__global__ void prep_kernel(const float* __restrict__ feat, unsigned short* __restrict__ fnorm,
                            float* __restrict__ inv_norm) {
    int wave = threadIdx.x >> 6, lane = threadIdx.x & 63;
    int row = blockIdx.x * 4 + wave;
    float4 v = *(const float4*)(feat + (size_t)row * D_K + lane * 4);
    float ss = v.x * v.x + v.y * v.y + v.z * v.z + v.w * v.w;
    #pragma unroll
    for (int off = 1; off < 64; off <<= 1) ss += __shfl_xor(ss, off);
    float inv = 1.0f / fmaxf(sqrtf(ss), 1e-12f);
    if (lane == 0) inv_norm[row] = inv;
    ushort4 o;
    o.x = f2bf(v.x * inv); o.y = f2bf(v.y * inv);
    o.z = f2bf(v.z * inv); o.w = f2bf(v.w * inv);
    *(ushort4*)(fnorm + (size_t)row * D_K + lane * 4) = o;
}

// -------- Kernel 2: per-class counts + sum(pos dots) via class-sum vectors --------
// gp = sum_c (||S_c||^2 - |c|) = sum over ordered same-label pairs (i!=j) of dot_ij  [fp32 path]
__global__ void hist_kernel(const float* __restrict__ feat, const int* __restrict__ labels,
                            const float* __restrict__ inv_norm,
                            int* __restrict__ cnt, float* __restrict__ gscal) {
    int c = blockIdx.x, tid = threadIdx.x;
    __shared__ unsigned short list[B_N];
    __shared__ int cntS;
    __shared__ float red[4];
    if (tid == 0) cntS = 0;
    __syncthreads();
    for (int r = tid; r < B_N; r += 256)
        if (labels[r] == c) { int p = atomicAdd(&cntS, 1); list[p] = (unsigned short)r; }
    __syncthreads();
    int n = cntS;
    float s = 0.f;                      // S_c[dim = tid]
    #pragma unroll 4
    for (int k = 0; k < n; ++k) {
        int r = list[k];
        s += feat[(size_t)r * D_K + tid] * inv_norm[r];
    }
    float v = s * s;
    #pragma unroll
    for (int off = 1; off < 64; off <<= 1) v += __shfl_xor(v, off);
    if ((tid & 63) == 0) red[tid >> 6] = v;
    __syncthreads();
    if (tid == 0) {
        float tot = red[0] + red[1] + red[2] + red[3];
        cnt[c] = n;
        atomicAdd(&gscal[0], tot - (float)n);
    }
}

// -------- Kernel 3: upper-triangular sim tiles, 8 waves, 64x32 per-wave tile --------
// G[slot][row] = {denom_e_sum, relax_e_sum}; each (slot,row) written exactly once.
__global__ __launch_bounds__(NT, 4) void main_kernel(
        const unsigned short* __restrict__ fnorm, const int* __restrict__ labels,
        float2* __restrict__ G, float* __restrict__ gscal) {
    int bid = blockIdx.x;
    int b = (int)((sqrtf(8.0f * bid + 1.0f) - 1.0f) * 0.5f);
    while ((b + 1) * (b + 2) / 2 <= bid) ++b;
    while (b * (b + 1) / 2 > bid) --b;
    int a = bid - b * (b + 1) / 2;
    const int row0 = a * TILE, col0 = b * TILE;
    const bool diag = (a == b);

    __shared__ short As[TILE * LDA];   // reused as Rbuf (float2[4][128]) in epilogue
    __shared__ short Bs[TILE * LDA];   // reused as Cbuf (float2[2][128])
    __shared__ int Ls[2 * TILE];
    __shared__ int ghs[8];

    const int tid = threadIdx.x;
    const int lane = tid & 63, wave = tid >> 6;
    const int wm = wave >> 2, wn = wave & 3;    // 2 (row) x 4 (col) waves; each 64x32
    const int l15 = lane & 15, lhi = lane >> 4;
    const short* fn = (const short*)fnorm;

    if (tid < 128) Ls[tid] = labels[row0 + tid];
    else if (tid < 256) Ls[tid] = labels[col0 + tid - 128];

    f32x4 acc[4][2];
    #pragma unroll
    for (int i = 0; i < 4; i++)
        #pragma unroll
        for (int j = 0; j < 2; j++) acc[i][j] = {0.f, 0.f, 0.f, 0.f};

    for (int kc = 0; kc < 4; ++kc) {
        #pragma unroll
        for (int li = 0; li < 2; ++li) {
            int id = tid + li * NT;           // 0..1023 over 128 rows x 8 16B-chunks
            int r = id >> 3, c8 = id & 7;
            *(short8*)&As[r * LDA + c8 * 8] =
                *(const short8*)&fn[(size_t)(row0 + r) * D_K + kc * 64 + c8 * 8];
            *(short8*)&Bs[r * LDA + c8 * 8] =
                *(const short8*)&fn[(size_t)(col0 + r) * D_K + kc * 64 + c8 * 8];
        }
        __syncthreads();
        #pragma unroll
        for (int ks = 0; ks < 2; ++ks) {
            short8 af[4], bfr[2];
            #pragma unroll
            for (int mi = 0; mi < 4; mi++)
                af[mi] = *(const short8*)&As[(wm * 64 + mi * 16 + l15) * LDA + ks * 32 + lhi * 8];
            #pragma unroll
            for (int ni = 0; ni < 2; ni++)
                bfr[ni] = *(const short8*)&Bs[(wn * 32 + ni * 16 + l15) * LDA + ks * 32 + lhi * 8];
            #pragma unroll
            for (int mi = 0; mi < 4; mi++)
                #pragma unroll
                for (int ni = 0; ni < 2; ni++)
                    acc[mi][ni] = __builtin_amdgcn_mfma_f32_16x16x32_bf16(af[mi], bfr[ni], acc[mi][ni], 0, 0, 0);
        }
        __syncthreads();
    }

    // ---- Epilogue. C/D layout: col = lane&15, row = (lane>>4)*4 + reg ----
    float2* Rbuf = (float2*)As;   // [wn 0..3][128]
    float2* Cbuf = (float2*)Bs;   // [wm 0..1][128]

    int lc[2], colg[2];
    #pragma unroll
    for (int ni = 0; ni < 2; ni++) {
        int c = wn * 32 + ni * 16 + l15;
        lc[ni] = Ls[128 + c];
        colg[ni] = col0 + c;
    }

    float cD[2] = {0.f, 0.f}, cR[2] = {0.f, 0.f};
    int nhi = 0;

    #pragma unroll
    for (int mi = 0; mi < 4; mi++) {
        #pragma unroll
        for (int reg = 0; reg < 4; reg++) {
            int rloc = wm * 64 + mi * 16 + lhi * 4 + reg;
            int rowg = row0 + rloc;
            int lr = Ls[rloc];
            float d = 0.f, rx = 0.f;
            #pragma unroll
            for (int ni = 0; ni < 2; ni++) {
                float dot = acc[mi][ni][reg];
                float e = __builtin_exp2f((dot - 1.0f) * KEXP);   // e^(sim-20), sim<=20
                bool notself = (rowg != colg[ni]);
                bool high = (lr == lc[ni]) && (dot > 0.7f) && notself;
                float ev = notself ? e : 0.f;
                float hv = high ? e : 0.f;
                d += ev; rx += hv;
                cD[ni] += ev; cR[ni] += hv;
                nhi += (int)__popcll(__ballot(high));
            }
            #pragma unroll
            for (int off = 1; off < 16; off <<= 1) {
                d += __shfl_xor(d, off);
                rx += __shfl_xor(rx, off);
            }
            if (l15 == 0) Rbuf[wn * 128 + rloc] = {d, rx};
        }
    }

    if (!diag) {
        #pragma unroll
        for (int ni = 0; ni < 2; ni++) {
            #pragma unroll
            for (int off = 16; off < 64; off <<= 1) {
                cD[ni] += __shfl_xor(cD[ni], off);
                cR[ni] += __shfl_xor(cR[ni], off);
            }
        }
        if (lhi == 0) {
            #pragma unroll
            for (int ni = 0; ni < 2; ni++) {
                int c = wn * 32 + ni * 16 + l15;
                Cbuf[wm * 128 + c] = {cD[ni], cR[ni]};
            }
        }
    }
    if (lane == 0) ghs[wave] = nhi;
    __syncthreads();

    if (tid < 128) {
        int r = tid;
        float2 a0 = Rbuf[r], a1 = Rbuf[128 + r], a2 = Rbuf[256 + r], a3 = Rbuf[384 + r];
        G[(size_t)b * B_N + row0 + r] = {a0.x + a1.x + a2.x + a3.x, a0.y + a1.y + a2.y + a3.y};
    } else if (tid < 256 && !diag) {
        int c = tid - 128;
        float2 a0 = Cbuf[c], a1 = Cbuf[128 + c];
        G[(size_t)a * B_N + col0 + c] = {a0.x + a1.x, a0.y + a1.y};
    }
    if (tid == 0) {
        float w = diag ? 1.0f : 2.0f;   // off-diag tile stands for (i,j) and (j,i)
        atomicAdd(&gscal[1], w * (float)(ghs[0] + ghs[1] + ghs[2] + ghs[3] +
                                          ghs[4] + ghs[5] + ghs[6] + ghs[7]));
    }
}

// -------- Kernel 4: per-row reduction over 64 slots (4 threads/row, coalesced) --------
__global__ void finalize1(const float2* __restrict__ G, const int* __restrict__ labels,
                          const int* __restrict__ cnt, double* __restrict__ part) {
    int lane = threadIdx.x & 63, q = threadIdx.x >> 6;   // q = slot quarter
    int r = blockIdx.x * 64 + lane;
    float d = 0.f, rx = 0.f;
    #pragma unroll
    for (int s = 0; s < 16; ++s) {
        float2 g = G[(size_t)(q * 16 + s) * B_N + r];
        d += g.x; rx += g.y;
    }
    __shared__ float2 sh[4][64];
    sh[q][lane] = {d, rx};
    __syncthreads();
    if (threadIdx.x < 64) {
        int rr = blockIdx.x * 64 + threadIdx.x;
        float2 t0 = sh[0][threadIdx.x], t1 = sh[1][threadIdx.x];
        float2 t2 = sh[2][threadIdx.x], t3 = sh[3][threadIdx.x];
        float dd = t0.x + t1.x + t2.x + t3.x;
        float rr2 = t0.y + t1.y + t2.y + t3.y;
        float np = (float)(cnt[labels[rr]] - 1);
        float ld = logf(dd + 1e-12f) + 20.0f;             // log_denom (shift 20)
        double s1 = (double)np * (double)ld;
        double s2 = (double)np;
        double s3 = (rr2 > 0.f) ? (double)logf(rr2 + 1.0f) : 0.0;  // baseline=0: sim_max=20
        #pragma unroll
        for (int off = 1; off < 64; off <<= 1) {
            s1 += __shfl_xor(s1, off);
            s2 += __shfl_xor(s2, off);
            s3 += __shfl_xor(s3, off);
        }
        if (threadIdx.x == 0) {
            part[blockIdx.x * 3 + 0] = s1;
            part[blockIdx.x * 3 + 1] = s2;
            part[blockIdx.x * 3 + 2] = s3;
        }
    }
}

// -------- Kernel 5: scalar assembly --------
__global__ void finalize2(const double* __restrict__ part, const float* __restrict__ gscal,
                          float* __restrict__ out) {
    if (threadIdx.x == 0) {
        double s1 = 0, s2 = 0, s3 = 0;
        for (int b = 0; b < 128; ++b) {
            s1 += part[b * 3 + 0];
            s2 += part[b * 3 + 1];
            s3 += part[b * 3 + 2];
        }
        double gp = (double)gscal[0];   // sum over ordered pos pairs of dot
        double gh = (double)gscal[1];   // count of high ordered pairs
        double scl = (s2 > 0.0) ? (s1 - 20.0 * gp) / fmax(s2, 1.0) : 0.0;
        double rel = (gh > 0.0) ? s3 / fmax(gh, 1.0) : 0.0;
        double tot = scl + rel;         // BETA = 1.0
        tot = fmin(fmax(tot, 0.0), 10.0);
        out[0] = (float)tot;
    }
}

extern "C" void kernel_launch(void* const* d_in, const int* in_sizes, int n_in,
                              void* d_out, int out_size, void* d_ws, size_t ws_size,
                              hipStream_t stream) {
    const float* feat = (const float*)d_in[0];
    const int* labels = (const int*)d_in[1];
    float* out = (float*)d_out;
    char* ws = (char*)d_ws;

    unsigned short* fnorm = (unsigned short*)(ws);                        // 4 MB
    float2* G        = (float2*)(ws + (size_t)4 * 1024 * 1024);           // 4 MB: [64][8192]
    float*  inv_norm = (float*)(ws + (size_t)8 * 1024 * 1024);            // 32 KB
    double* part     = (double*)(ws + (size_t)8 * 1024 * 1024 + 32768);   // 3 KB
    float*  gscal    = (float*)(ws + (size_t)8 * 1024 * 1024 + 36864);    // 8 B
    int*    cnt      = (int*)(ws + (size_t)8 * 1024 * 1024 + 40960);      // 400 B

    hipMemsetAsync(gscal, 0, 2 * sizeof(float), stream);
    prep_kernel<<<B_N / 4, 256, 0, stream>>>(feat, fnorm, inv_norm);
    hist_kernel<<<NCLS, 256, 0, stream>>>(feat, labels, inv_norm, cnt, gscal);
    main_kernel<<<NPAIR, NT, 0, stream>>>(fnorm, labels, G, gscal);
    finalize1<<<B_N / 64, 256, 0, stream>>>(G, labels, cnt, part);
    finalize2<<<1, 64, 0, stream>>>(part, gscal, out);
    (void)in_sizes; (void)n_in; (void)out_size; (void)ws_size;
}

// Round 5
// 128.659 us; speedup vs baseline: 1.1848x; 1.1848x over previous
//
#include <hip/hip_runtime.h>
#include <hip/hip_bf16.h>
#include <math.h>

#define B_N 8192
#define D_K 256
#define TILE 128
#define NT 512
#define NBLK 64             // B_N / TILE
#define NPAIR 2080          // NBLK*(NBLK+1)/2 upper-triangular tile pairs
#define NCLS 100
#define KEXP 28.8539008177792681f   // 20*log2(e): e^(sim-20) = 2^((dot-1)*KEXP)

typedef __attribute__((ext_vector_type(8))) short short8;
typedef __attribute__((ext_vector_type(4))) float f32x4;

__device__ __forceinline__ unsigned short f2bf(float x) {
    unsigned int u = __float_as_uint(x);
    unsigned int r = (u + 0x7FFFu + ((u >> 16) & 1u)) >> 16;
    return (unsigned short)r;
}

// async global->LDS, 16B per lane: dest = (wave-uniform) lds base + lane*16
__device__ __forceinline__ void gload_lds16(const short* g, short* l) {
    __builtin_amdgcn_global_load_lds(
        (const __attribute__((address_space(1))) void*)g,
        (__attribute__((address_space(3))) void*)l, 16, 0, 0);
}

// -------- Kernel 1: normalize rows -> bf16 + inv_norm; also zero gscal --------
__global__ void prep_kernel(const float* __restrict__ feat, unsigned short* __restrict__ fnorm,
                            float* __restrict__ inv_norm, float* __restrict__ gscal) {
    if (blockIdx.x == 0 && threadIdx.x < 2) gscal[threadIdx.x] = 0.f;
    int wave = threadIdx.x >> 6, lane = threadIdx.x & 63;
    int row = blockIdx.x * 4 + wave;
    float4 v = *(const float4*)(feat + (size_t)row * D_K + lane * 4);
    float ss = v.x * v.x + v.y * v.y + v.z * v.z + v.w * v.w;
    #pragma unroll
    for (int off = 1; off < 64; off <<= 1) ss += __shfl_xor(ss, off);
    float inv = 1.0f / fmaxf(sqrtf(ss), 1e-12f);
    if (lane == 0) inv_norm[row] = inv;
    ushort4 o;
    o.x = f2bf(v.x * inv); o.y = f2bf(v.y * inv);
    o.z = f2bf(v.z * inv); o.w = f2bf(v.w * inv);
    *(ushort4*)(fnorm + (size_t)row * D_K + lane * 4) = o;
}

// -------- Kernel 2: per-class counts + sum(pos dots) via class-sum vectors --------
__global__ void hist_kernel(const float* __restrict__ feat, const int* __restrict__ labels,
                            const float* __restrict__ inv_norm,
                            int* __restrict__ cnt, float* __restrict__ gscal) {
    int c = blockIdx.x, tid = threadIdx.x;
    __shared__ unsigned short list[B_N];
    __shared__ int cntS;
    __shared__ float red[4];
    if (tid == 0) cntS = 0;
    __syncthreads();
    for (int r = tid; r < B_N; r += 256)
        if (labels[r] == c) { int p = atomicAdd(&cntS, 1); list[p] = (unsigned short)r; }
    __syncthreads();
    int n = cntS;
    float s = 0.f;                      // S_c[dim = tid]
    #pragma unroll 8
    for (int k = 0; k < n; ++k) {
        int r = list[k];
        s += feat[(size_t)r * D_K + tid] * inv_norm[r];
    }
    float v = s * s;
    #pragma unroll
    for (int off = 1; off < 64; off <<= 1) v += __shfl_xor(v, off);
    if ((tid & 63) == 0) red[tid >> 6] = v;
    __syncthreads();
    if (tid == 0) {
        float tot = red[0] + red[1] + red[2] + red[3];
        cnt[c] = n;
        atomicAdd(&gscal[0], tot - (float)n);
    }
}

// -------- Kernel 3: upper-triangular sim tiles --------
// LDS layout: LDS[r][c] = global chunk (c ^ (r&7)) -- XOR swizzle keeps global_load_lds
// linear (lane*16) while making fragment reads 2-way-max on banks.
__global__ __launch_bounds__(NT, 4) void main_kernel(
        const unsigned short* __restrict__ fnorm, const int* __restrict__ labels,
        float2* __restrict__ G, float* __restrict__ gscal) {
    int bid = blockIdx.x;
    int b = (int)((sqrtf(8.0f * bid + 1.0f) - 1.0f) * 0.5f);
    while ((b + 1) * (b + 2) / 2 <= bid) ++b;
    while (b * (b + 1) / 2 > bid) --b;
    int a = bid - b * (b + 1) / 2;
    const int row0 = a * TILE, col0 = b * TILE;
    const bool diag = (a == b);

    __shared__ short As[TILE * 64];    // 16 KB, no pad; reused as Rbuf float2[4][128]
    __shared__ short Bs[TILE * 64];    // 16 KB; reused as Cbuf float2[2][128]
    __shared__ int Ls[2 * TILE];
    __shared__ int ghs[8];

    const int tid = threadIdx.x;
    const int lane = tid & 63, wave = tid >> 6;
    const int wm = wave >> 2, wn = wave & 3;    // 2 (row) x 4 (col) waves; each 64x32
    const int l15 = lane & 15, lhi = lane >> 4;
    const short* fn = (const short*)fnorm;

    if (tid < 128) Ls[tid] = labels[row0 + tid];
    else if (tid < 256) Ls[tid] = labels[col0 + tid - 128];
    if (lane == 0) ghs[wave] = 0;

    f32x4 acc[4][2];
    #pragma unroll
    for (int i = 0; i < 4; i++)
        #pragma unroll
        for (int j = 0; j < 2; j++) acc[i][j] = {0.f, 0.f, 0.f, 0.f};

    for (int kc = 0; kc < 4; ++kc) {
        #pragma unroll
        for (int li = 0; li < 2; ++li) {
            int id = tid + li * NT;            // 0..1023: 128 rows x 8 chunks of 16B
            int r = id >> 3, c = id & 7;
            int cs = c ^ (r & 7);              // swizzled source chunk
            int ub = (id & ~63) * 8;           // wave-uniform LDS short offset
            gload_lds16(fn + (size_t)(row0 + r) * D_K + kc * 64 + cs * 8, &As[ub]);
            gload_lds16(fn + (size_t)(col0 + r) * D_K + kc * 64 + cs * 8, &Bs[ub]);
        }
        __syncthreads();
        #pragma unroll
        for (int ks = 0; ks < 2; ++ks) {
            short8 af[4], bfr[2];
            #pragma unroll
            for (int mi = 0; mi < 4; mi++) {
                int row = wm * 64 + mi * 16 + l15;
                int ch = (ks * 4 + lhi) ^ (l15 & 7);
                af[mi] = *(const short8*)&As[row * 64 + ch * 8];
            }
            #pragma unroll
            for (int ni = 0; ni < 2; ni++) {
                int row = wn * 32 + ni * 16 + l15;
                int ch = (ks * 4 + lhi) ^ (l15 & 7);
                bfr[ni] = *(const short8*)&Bs[row * 64 + ch * 8];
            }
            #pragma unroll
            for (int mi = 0; mi < 4; mi++)
                #pragma unroll
                for (int ni = 0; ni < 2; ni++)
                    acc[mi][ni] = __builtin_amdgcn_mfma_f32_16x16x32_bf16(af[mi], bfr[ni], acc[mi][ni], 0, 0, 0);
        }
        __syncthreads();
    }

    // ---- Epilogue. C/D layout: col = lane&15, row = (lane>>4)*4 + reg ----
    float2* Rbuf = (float2*)As;   // [wn 0..3][128]
    float2* Cbuf = (float2*)Bs;   // [wm 0..1][128]

    int lc[2], colg[2];
    #pragma unroll
    for (int ni = 0; ni < 2; ni++) {
        int c = wn * 32 + ni * 16 + l15;
        lc[ni] = Ls[128 + c];
        colg[ni] = col0 + c;
    }

    float cD[2] = {0.f, 0.f};
    unsigned int hmask = 0;   // bit (pair*2+ni) = high

    #pragma unroll
    for (int mi = 0; mi < 4; mi++) {
        #pragma unroll
        for (int reg = 0; reg < 4; reg++) {
            int rloc = wm * 64 + mi * 16 + lhi * 4 + reg;
            int rowg = row0 + rloc;
            int lr = Ls[rloc];
            float d = 0.f;
            #pragma unroll
            for (int ni = 0; ni < 2; ni++) {
                float dot = acc[mi][ni][reg];
                float e = __builtin_exp2f((dot - 1.0f) * KEXP);   // e^(sim-20), sim<=20
                bool ns = (rowg != colg[ni]);
                float ev = ns ? e : 0.f;
                d += ev; cD[ni] += ev;
                bool hi = ns && (lr == lc[ni]) && (dot > 0.7f);
                hmask |= hi ? (1u << ((mi * 4 + reg) * 2 + ni)) : 0u;
            }
            #pragma unroll
            for (int off = 1; off < 16; off <<= 1) d += __shfl_xor(d, off);
            if (l15 == 0) Rbuf[wn * 128 + rloc] = {d, 0.f};
        }
    }

    if (!diag) {
        #pragma unroll
        for (int ni = 0; ni < 2; ni++) {
            #pragma unroll
            for (int off = 16; off < 64; off <<= 1) cD[ni] += __shfl_xor(cD[ni], off);
        }
        if (lhi == 0) {
            #pragma unroll
            for (int ni = 0; ni < 2; ni++)
                Cbuf[wm * 128 + wn * 32 + ni * 16 + l15] = {cD[ni], 0.f};
        }
    }

    // ---- Rare path: any high-similarity positive in this wave ----
    if (__any(hmask != 0)) {
        float cR[2] = {0.f, 0.f};
        #pragma unroll
        for (int mi = 0; mi < 4; mi++) {
            #pragma unroll
            for (int reg = 0; reg < 4; reg++) {
                int rloc = wm * 64 + mi * 16 + lhi * 4 + reg;
                float rx = 0.f;
                #pragma unroll
                for (int ni = 0; ni < 2; ni++) {
                    if (hmask & (1u << ((mi * 4 + reg) * 2 + ni))) {
                        float e = __builtin_exp2f((acc[mi][ni][reg] - 1.0f) * KEXP);
                        rx += e; cR[ni] += e;
                    }
                }
                #pragma unroll
                for (int off = 1; off < 16; off <<= 1) rx += __shfl_xor(rx, off);
                if (l15 == 0) Rbuf[wn * 128 + rloc].y = rx;
            }
        }
        if (!diag) {
            #pragma unroll
            for (int ni = 0; ni < 2; ni++) {
                #pragma unroll
                for (int off = 16; off < 64; off <<= 1) cR[ni] += __shfl_xor(cR[ni], off);
            }
            if (lhi == 0) {
                #pragma unroll
                for (int ni = 0; ni < 2; ni++)
                    Cbuf[wm * 128 + wn * 32 + ni * 16 + l15].y = cR[ni];
            }
        }
        int nhi = __popc(hmask);
        #pragma unroll
        for (int off = 1; off < 64; off <<= 1) nhi += __shfl_xor(nhi, off);
        if (lane == 0) ghs[wave] = nhi;
    }
    __syncthreads();

    if (tid < 128) {
        int r = tid;
        float2 a0 = Rbuf[r], a1 = Rbuf[128 + r], a2 = Rbuf[256 + r], a3 = Rbuf[384 + r];
        G[(size_t)b * B_N + row0 + r] = {a0.x + a1.x + a2.x + a3.x, a0.y + a1.y + a2.y + a3.y};
    } else if (tid < 256 && !diag) {
        int c = tid - 128;
        float2 a0 = Cbuf[c], a1 = Cbuf[128 + c];
        G[(size_t)a * B_N + col0 + c] = {a0.x + a1.x, a0.y + a1.y};
    }
    if (tid == 0) {
        int tot = ghs[0] + ghs[1] + ghs[2] + ghs[3] + ghs[4] + ghs[5] + ghs[6] + ghs[7];
        if (tot > 0) {
            float w = diag ? 1.0f : 2.0f;
            atomicAdd(&gscal[1], w * (float)tot);
        }
    }
}

// -------- Kernel 4: per-row reduction over 64 slots (4 threads/row, coalesced) --------
__global__ void finalize1(const float2* __restrict__ G, const int* __restrict__ labels,
                          const int* __restrict__ cnt, double* __restrict__ part) {
    int lane = threadIdx.x & 63, q = threadIdx.x >> 6;   // q = slot quarter
    int r = blockIdx.x * 64 + lane;
    float d = 0.f, rx = 0.f;
    #pragma unroll
    for (int s = 0; s < 16; ++s) {
        float2 g = G[(size_t)(q * 16 + s) * B_N + r];
        d += g.x; rx += g.y;
    }
    __shared__ float2 sh[4][64];
    sh[q][lane] = {d, rx};
    __syncthreads();
    if (threadIdx.x < 64) {
        int rr = blockIdx.x * 64 + threadIdx.x;
        float2 t0 = sh[0][threadIdx.x], t1 = sh[1][threadIdx.x];
        float2 t2 = sh[2][threadIdx.x], t3 = sh[3][threadIdx.x];
        float dd = t0.x + t1.x + t2.x + t3.x;
        float rr2 = t0.y + t1.y + t2.y + t3.y;
        float np = (float)(cnt[labels[rr]] - 1);
        float ld = logf(dd + 1e-12f) + 20.0f;             // log_denom (shift 20)
        double s1 = (double)np * (double)ld;
        double s2 = (double)np;
        double s3 = (rr2 > 0.f) ? (double)logf(rr2 + 1.0f) : 0.0;  // baseline=0: sim_max=20
        #pragma unroll
        for (int off = 1; off < 64; off <<= 1) {
            s1 += __shfl_xor(s1, off);
            s2 += __shfl_xor(s2, off);
            s3 += __shfl_xor(s3, off);
        }
        if (threadIdx.x == 0) {
            part[blockIdx.x * 3 + 0] = s1;
            part[blockIdx.x * 3 + 1] = s2;
            part[blockIdx.x * 3 + 2] = s3;
        }
    }
}

// -------- Kernel 5: scalar assembly (parallel) --------
__global__ void finalize2(const double* __restrict__ part, const float* __restrict__ gscal,
                          float* __restrict__ out) {
    int t = threadIdx.x;   // 128 threads = 2 waves
    double s1 = part[t * 3 + 0], s2 = part[t * 3 + 1], s3 = part[t * 3 + 2];
    #pragma unroll
    for (int off = 1; off < 64; off <<= 1) {
        s1 += __shfl_xor(s1, off);
        s2 += __shfl_xor(s2, off);
        s3 += __shfl_xor(s3, off);
    }
    __shared__ double sh[2][3];
    int wave = t >> 6, lane = t & 63;
    if (lane == 0) { sh[wave][0] = s1; sh[wave][1] = s2; sh[wave][2] = s3; }
    __syncthreads();
    if (t == 0) {
        double a1 = sh[0][0] + sh[1][0];
        double a2 = sh[0][1] + sh[1][1];
        double a3 = sh[0][2] + sh[1][2];
        double gp = (double)gscal[0];   // sum over ordered pos pairs of dot
        double gh = (double)gscal[1];   // count of high ordered pairs
        double scl = (a2 > 0.0) ? (a1 - 20.0 * gp) / fmax(a2, 1.0) : 0.0;
        double rel = (gh > 0.0) ? a3 / fmax(gh, 1.0) : 0.0;
        double tot = scl + rel;         // BETA = 1.0
        tot = fmin(fmax(tot, 0.0), 10.0);
        out[0] = (float)tot;
    }
}

extern "C" void kernel_launch(void* const* d_in, const int* in_sizes, int n_in,
                              void* d_out, int out_size, void* d_ws, size_t ws_size,
                              hipStream_t stream) {
    const float* feat = (const float*)d_in[0];
    const int* labels = (const int*)d_in[1];
    float* out = (float*)d_out;
    char* ws = (char*)d_ws;

    unsigned short* fnorm = (unsigned short*)(ws);                        // 4 MB
    float2* G        = (float2*)(ws + (size_t)4 * 1024 * 1024);           // 4 MB: [64][8192]
    float*  inv_norm = (float*)(ws + (size_t)8 * 1024 * 1024);            // 32 KB
    double* part     = (double*)(ws + (size_t)8 * 1024 * 1024 + 32768);   // 3 KB
    float*  gscal    = (float*)(ws + (size_t)8 * 1024 * 1024 + 36864);    // 8 B
    int*    cnt      = (int*)(ws + (size_t)8 * 1024 * 1024 + 40960);      // 400 B

    prep_kernel<<<B_N / 4, 256, 0, stream>>>(feat, fnorm, inv_norm, gscal);
    hist_kernel<<<NCLS, 256, 0, stream>>>(feat, labels, inv_norm, cnt, gscal);
    main_kernel<<<NPAIR, NT, 0, stream>>>(fnorm, labels, G, gscal);
    finalize1<<<B_N / 64, 256, 0, stream>>>(G, labels, cnt, part);
    finalize2<<<1, 128, 0, stream>>>(part, gscal, out);
    (void)in_sizes; (void)n_in; (void)out_size; (void)ws_size;
}